// Round 1
// baseline (946.542 us; speedup 1.0000x reference)
//
#include <hip/hip_runtime.h>
#include <hip/hip_bf16.h>
#include <math.h>

// Problem constants
#define B_  512
#define XD_ 32768
#define PD_ 512
#define D_  64
#define H_  128
#define G1_ 1024

__device__ __forceinline__ float eluf(float v) { return v > 0.f ? v : expm1f(v); }

// ---------------------------------------------------------------------------
// K1: split-K GEMM  part[ks] += x[512,32768] @ Wg1[32768,1024]
// grid (8,16,4), 256 threads, 64x64 tile, 4x4 micro, BK=32
// ---------------------------------------------------------------------------
__global__ __launch_bounds__(256) void k_gemm1(const float* __restrict__ x,
                                               const float* __restrict__ Wg1,
                                               float* __restrict__ part) {
    __shared__ float As[32][64];  // transposed: As[k][m]
    __shared__ float Bs[32][64];
    const int mt = blockIdx.x, nt = blockIdx.y, ks = blockIdx.z;
    const int t = threadIdx.x;
    const int trow = t >> 4, tcol = t & 15;
    const int K = XD_, N = G1_;
    const int k0 = ks * 8192;

    float acc[4][4] = {};
    const float* xA = x + (size_t)(mt * 64) * K + k0;
    const float* Bg = Wg1 + (size_t)k0 * N + nt * 64;

    for (int kt = 0; kt < 8192; kt += 32) {
        // A: 64 rows x 32 cols
        #pragma unroll
        for (int i = 0; i < 2; i++) {
            int id = i * 256 + t;
            int r = id >> 3;            // 0..63
            int c4 = (id & 7) * 4;      // 0..28
            float4 v = *(const float4*)(xA + (size_t)r * K + kt + c4);
            As[c4 + 0][r] = v.x; As[c4 + 1][r] = v.y;
            As[c4 + 2][r] = v.z; As[c4 + 3][r] = v.w;
        }
        // B: 32 rows x 64 cols
        #pragma unroll
        for (int i = 0; i < 2; i++) {
            int id = i * 256 + t;
            int r = id >> 4;            // 0..31
            int c4 = (id & 15) * 4;     // 0..60
            *(float4*)&Bs[r][c4] = *(const float4*)(Bg + (size_t)(kt + r) * N + c4);
        }
        __syncthreads();
        #pragma unroll
        for (int k = 0; k < 32; k++) {
            float4 av = *(const float4*)&As[k][trow * 4];
            float4 bv = *(const float4*)&Bs[k][tcol * 4];
            float a[4] = {av.x, av.y, av.z, av.w};
            float b[4] = {bv.x, bv.y, bv.z, bv.w};
            #pragma unroll
            for (int i = 0; i < 4; i++)
                #pragma unroll
                for (int j = 0; j < 4; j++)
                    acc[i][j] = fmaf(a[i], b[j], acc[i][j]);
        }
        __syncthreads();
    }
    float* P = part + (size_t)ks * (B_ * G1_);
    #pragma unroll
    for (int i = 0; i < 4; i++) {
        int r = mt * 64 + trow * 4 + i;
        int c = nt * 64 + tcol * 4;
        float* dst = P + (size_t)r * G1_ + c;
        dst[0] = acc[i][0]; dst[1] = acc[i][1]; dst[2] = acc[i][2]; dst[3] = acc[i][3];
    }
}

// K1b: reduce split-K partials + bias + elu -> G[512,1024]
__global__ __launch_bounds__(256) void k_red1(const float* __restrict__ part,
                                              const float* __restrict__ bg1,
                                              float* __restrict__ G) {
    int idx = blockIdx.x * 256 + threadIdx.x;  // 524288 total
    const int S = B_ * G1_;
    float s = part[idx] + part[idx + S] + part[idx + 2 * S] + part[idx + 3 * S]
            + bg1[idx & (G1_ - 1)];
    G[idx] = eluf(s);
}

// ---------------------------------------------------------------------------
// K2: h = elu(G[512,1024] @ Wg2[1024,512] + bg2)   grid (8,8)
// ---------------------------------------------------------------------------
__global__ __launch_bounds__(256) void k_gemm2(const float* __restrict__ G,
                                               const float* __restrict__ Wg2,
                                               const float* __restrict__ bg2,
                                               float* __restrict__ h) {
    __shared__ float As[32][64];
    __shared__ float Bs[32][64];
    const int mt = blockIdx.x, nt = blockIdx.y;
    const int t = threadIdx.x;
    const int trow = t >> 4, tcol = t & 15;
    const int K = G1_, N = PD_;

    float acc[4][4] = {};
    const float* Ag = G + (size_t)(mt * 64) * K;
    const float* Bg = Wg2 + nt * 64;

    for (int kt = 0; kt < K; kt += 32) {
        #pragma unroll
        for (int i = 0; i < 2; i++) {
            int id = i * 256 + t;
            int r = id >> 3;
            int c4 = (id & 7) * 4;
            float4 v = *(const float4*)(Ag + (size_t)r * K + kt + c4);
            As[c4 + 0][r] = v.x; As[c4 + 1][r] = v.y;
            As[c4 + 2][r] = v.z; As[c4 + 3][r] = v.w;
        }
        #pragma unroll
        for (int i = 0; i < 2; i++) {
            int id = i * 256 + t;
            int r = id >> 4;
            int c4 = (id & 15) * 4;
            *(float4*)&Bs[r][c4] = *(const float4*)(Bg + (size_t)(kt + r) * N + c4);
        }
        __syncthreads();
        #pragma unroll
        for (int k = 0; k < 32; k++) {
            float4 av = *(const float4*)&As[k][trow * 4];
            float4 bv = *(const float4*)&Bs[k][tcol * 4];
            float a[4] = {av.x, av.y, av.z, av.w};
            float b[4] = {bv.x, bv.y, bv.z, bv.w};
            #pragma unroll
            for (int i = 0; i < 4; i++)
                #pragma unroll
                for (int j = 0; j < 4; j++)
                    acc[i][j] = fmaf(a[i], b[j], acc[i][j]);
        }
        __syncthreads();
    }
    #pragma unroll
    for (int i = 0; i < 4; i++) {
        int r = mt * 64 + trow * 4 + i;
        int c = nt * 64 + tcol * 4;
        #pragma unroll
        for (int j = 0; j < 4; j++)
            h[(size_t)r * PD_ + c + j] = eluf(acc[i][j] + bg2[c + j]);
    }
}

// ---------------------------------------------------------------------------
// K3: hWh[b,d,h] = sum_p h[b,p] * Wh[d,p,h]   grid (8 mtiles, 64 d)
// 64x128 tile, 4x8 micro, BK=32
// ---------------------------------------------------------------------------
__global__ __launch_bounds__(256) void k_hwh(const float* __restrict__ h,
                                             const float* __restrict__ Wh,
                                             float* __restrict__ hWh) {
    __shared__ float As[32][64];
    __shared__ float Bs[32][128];
    const int mt = blockIdx.x, d = blockIdx.y;
    const int t = threadIdx.x;
    const int trow = t >> 4, tcol = t & 15;
    const int K = PD_;

    float acc[4][8] = {};
    const float* Ag = h + (size_t)(mt * 64) * K;
    const float* Bg = Wh + (size_t)d * K * H_;

    for (int kt = 0; kt < K; kt += 32) {
        #pragma unroll
        for (int i = 0; i < 2; i++) {
            int id = i * 256 + t;
            int r = id >> 3;
            int c4 = (id & 7) * 4;
            float4 v = *(const float4*)(Ag + (size_t)r * K + kt + c4);
            As[c4 + 0][r] = v.x; As[c4 + 1][r] = v.y;
            As[c4 + 2][r] = v.z; As[c4 + 3][r] = v.w;
        }
        #pragma unroll
        for (int i = 0; i < 4; i++) {
            int id = i * 256 + t;
            int r = id >> 5;            // 0..31
            int c4 = (id & 31) * 4;     // 0..124
            *(float4*)&Bs[r][c4] = *(const float4*)(Bg + (size_t)(kt + r) * H_ + c4);
        }
        __syncthreads();
        #pragma unroll
        for (int k = 0; k < 32; k++) {
            float4 av = *(const float4*)&As[k][trow * 4];
            float4 b0 = *(const float4*)&Bs[k][tcol * 8];
            float4 b1v = *(const float4*)&Bs[k][tcol * 8 + 4];
            float a[4] = {av.x, av.y, av.z, av.w};
            float b[8] = {b0.x, b0.y, b0.z, b0.w, b1v.x, b1v.y, b1v.z, b1v.w};
            #pragma unroll
            for (int i = 0; i < 4; i++)
                #pragma unroll
                for (int j = 0; j < 8; j++)
                    acc[i][j] = fmaf(a[i], b[j], acc[i][j]);
        }
        __syncthreads();
    }
    #pragma unroll
    for (int i = 0; i < 4; i++) {
        int bb = mt * 64 + trow * 4 + i;
        float* dst = hWh + (size_t)bb * (D_ * H_) + d * H_ + tcol * 8;
        #pragma unroll
        for (int j = 0; j < 8; j++) dst[j] = acc[i][j];
    }
}

// ---------------------------------------------------------------------------
// K4: heads. grid (8 bchunks, 64 d). Two passes (joint, marg).
// a1 built transposed in LDS, a2-GEMM 64x128, fused score epilogue.
// ---------------------------------------------------------------------------
__global__ __launch_bounds__(256) void k_heads(const float* __restrict__ hWh,
                                               const float* __restrict__ z,
                                               const int* __restrict__ perm,
                                               const float* __restrict__ Wz,
                                               const float* __restrict__ b1,
                                               const float* __restrict__ W2,
                                               const float* __restrict__ b2,
                                               const float* __restrict__ W3,
                                               const float* __restrict__ b3,
                                               float* __restrict__ jpart,
                                               float* __restrict__ epart) {
    const int chunk = blockIdx.x;   // 0..7
    const int d = blockIdx.y;       // 0..63
    const int t = threadIdx.x;
    const int b0 = chunk * 64;
    __shared__ float a1T[128][64];  // [h][b]
    __shared__ float Bs[32][128];
    __shared__ float sred[64][16];
    const int trow = t >> 4, tcol = t & 15;
    const float* W2d = W2 + (size_t)d * H_ * H_;
    const float* Wzd = Wz + d * H_;
    const float* b1d = b1 + d * H_;
    const float* b2d = b2 + d * H_;
    const float* W3d = W3 + d * H_;

    float result0 = 0.f, result1 = 0.f;
    for (int pass = 0; pass < 2; pass++) {
        __syncthreads();
        // build a1T: thread handles b-row i = t>>2, h-range (t&3)*32..+31
        {
            int i = t >> 2;
            int bb = b0 + i;
            int src = (pass == 0) ? bb : perm[bb];
            float zv = z[bb * D_ + d];
            const float* hrow = hWh + (size_t)src * (D_ * H_) + d * H_;
            int h0 = (t & 3) * 32;
            #pragma unroll
            for (int hh = 0; hh < 32; hh += 4) {
                float4 v = *(const float4*)(hrow + h0 + hh);
                float4 w = *(const float4*)(Wzd + h0 + hh);
                float4 bb1 = *(const float4*)(b1d + h0 + hh);
                a1T[h0 + hh + 0][i] = eluf(v.x + zv * w.x + bb1.x);
                a1T[h0 + hh + 1][i] = eluf(v.y + zv * w.y + bb1.y);
                a1T[h0 + hh + 2][i] = eluf(v.z + zv * w.z + bb1.z);
                a1T[h0 + hh + 3][i] = eluf(v.w + zv * w.w + bb1.w);
            }
        }
        __syncthreads();
        float acc[4][8] = {};
        for (int kt = 0; kt < H_; kt += 32) {
            #pragma unroll
            for (int i2 = 0; i2 < 4; i2++) {
                int id = i2 * 256 + t;
                int r = id >> 5;
                int c4 = (id & 31) * 4;
                *(float4*)&Bs[r][c4] = *(const float4*)(W2d + (size_t)(kt + r) * H_ + c4);
            }
            __syncthreads();
            #pragma unroll
            for (int k = 0; k < 32; k++) {
                float4 av = *(const float4*)&a1T[kt + k][trow * 4];
                float4 bv0 = *(const float4*)&Bs[k][tcol * 8];
                float4 bv1 = *(const float4*)&Bs[k][tcol * 8 + 4];
                float a[4] = {av.x, av.y, av.z, av.w};
                float b[8] = {bv0.x, bv0.y, bv0.z, bv0.w, bv1.x, bv1.y, bv1.z, bv1.w};
                #pragma unroll
                for (int i = 0; i < 4; i++)
                    #pragma unroll
                    for (int j = 0; j < 8; j++)
                        acc[i][j] = fmaf(a[i], b[j], acc[i][j]);
            }
            __syncthreads();
        }
        // epilogue: a2 = elu(acc + b2), partial score = sum a2*W3
        #pragma unroll
        for (int i = 0; i < 4; i++) {
            float s = 0.f;
            #pragma unroll
            for (int j = 0; j < 8; j++) {
                int c = tcol * 8 + j;
                float a2v = eluf(acc[i][j] + b2d[c]);
                s = fmaf(a2v, W3d[c], s);
            }
            sred[trow * 4 + i][tcol] = s;
        }
        __syncthreads();
        float val = 0.f;
        if (t < 64) {
            float s = b3[d];
            #pragma unroll
            for (int c = 0; c < 16; c++) s += sred[t][c];
            val = (pass == 0) ? s : expf(s);
            #pragma unroll
            for (int off = 32; off > 0; off >>= 1)
                val += __shfl_down(val, off, 64);
        }
        if (t == 0) { if (pass == 0) result0 = val; else result1 = val; }
    }
    if (t == 0) {
        jpart[d * 8 + chunk] = result0;
        epart[d * 8 + chunk] = result1;
    }
}

// K5: final scalar. 1 block, 64 threads (one per d).
__global__ void k_final(const float* __restrict__ jpart,
                        const float* __restrict__ epart,
                        float* __restrict__ out) {
    int t = threadIdx.x;
    float mj = 0.f, me = 0.f;
    #pragma unroll
    for (int c = 0; c < 8; c++) { mj += jpart[t * 8 + c]; me += epart[t * 8 + c]; }
    mj *= (1.f / 512.f);
    me *= (1.f / 512.f);
    float mi = mj - logf(me);
    #pragma unroll
    for (int off = 32; off > 0; off >>= 1) mi += __shfl_down(mi, off, 64);
    if (t == 0) out[0] = -mi * (1.f / 64.f);
}

extern "C" void kernel_launch(void* const* d_in, const int* in_sizes, int n_in,
                              void* d_out, int out_size, void* d_ws, size_t ws_size,
                              hipStream_t stream) {
    const float* x   = (const float*)d_in[0];
    const float* z   = (const float*)d_in[1];
    const int*  perm = (const int*)d_in[2];
    const float* Wg1 = (const float*)d_in[3];
    const float* bg1 = (const float*)d_in[4];
    const float* Wg2 = (const float*)d_in[5];
    const float* bg2 = (const float*)d_in[6];
    const float* Wh  = (const float*)d_in[7];
    const float* Wz  = (const float*)d_in[8];
    const float* b1  = (const float*)d_in[9];
    const float* W2  = (const float*)d_in[10];
    const float* b2  = (const float*)d_in[11];
    const float* W3  = (const float*)d_in[12];
    const float* b3  = (const float*)d_in[13];
    float* out = (float*)d_out;

    float* ws = (float*)d_ws;
    float* G     = ws;                        // 524288 floats
    float* h     = ws + 524288;               // 262144
    float* hWh   = ws + 786432;               // 4194304
    float* part  = ws + 786432;               // 2097152 (overlaps hWh; dead before K3)
    float* jpart = ws + 786432 + 4194304;     // 512
    float* epart = jpart + 512;               // 512

    k_gemm1<<<dim3(8, 16, 4), 256, 0, stream>>>(x, Wg1, part);
    k_red1<<<2048, 256, 0, stream>>>(part, bg1, G);
    k_gemm2<<<dim3(8, 8), 256, 0, stream>>>(G, Wg2, bg2, h);
    k_hwh<<<dim3(8, 64), 256, 0, stream>>>(h, Wh, hWh);
    k_heads<<<dim3(8, 64), 256, 0, stream>>>(hWh, z, perm, Wz, b1, W2, b2, W3, b3,
                                             jpart, epart);
    k_final<<<1, 64, 0, stream>>>(jpart, epart, out);
}

// Round 2
// 564.160 us; speedup vs baseline: 1.6778x; 1.6778x over previous
//
#include <hip/hip_runtime.h>
#include <hip/hip_bf16.h>
#include <math.h>

// Problem constants
#define B_  512
#define XD_ 32768
#define PD_ 512
#define D_  64
#define H_  128
#define G1_ 1024

typedef __attribute__((ext_vector_type(8))) short short8v;
typedef __attribute__((ext_vector_type(4))) float floatx4;

__device__ __forceinline__ float eluf(float v) { return v > 0.f ? v : expm1f(v); }

// split fp32 -> bf16 hi (RNE) + bf16 lo (truncated residual)
__device__ __forceinline__ void split8(const float* c, short8v& h, short8v& l) {
    #pragma unroll
    for (int j = 0; j < 8; j++) {
        unsigned u = __float_as_uint(c[j]);
        unsigned r = (u + 0x7FFFu + ((u >> 16) & 1u)) >> 16;
        h[j] = (short)r;
        float res = c[j] - __uint_as_float(r << 16);
        l[j] = (short)(__float_as_uint(res) >> 16);
    }
}

// ---------------------------------------------------------------------------
// K1: split-bf16 MFMA GEMM  part[ks] = x[512,32768] @ Wg1[32768,1024] slice
// grid (8 nt, 8 mt, 8 ks), 256 thr. Tile 64x128, BK=32, K-slice 4096.
// LDS fragment layout with n^kc swizzle; 3-term split-bf16 MFMA.
// ---------------------------------------------------------------------------
__global__ __launch_bounds__(256) void k_gemm1m(const float* __restrict__ x,
                                                const float* __restrict__ Wg1,
                                                float* __restrict__ part) {
    __shared__ ushort Ah[4 * 64 * 8], Al[4 * 64 * 8];     // 4 KB each
    __shared__ ushort Bh[4 * 128 * 8], Bl[4 * 128 * 8];   // 8 KB each
    const int nt = blockIdx.x, mt = blockIdx.y, ks = blockIdx.z;
    const int t = threadIdx.x;
    const int w = t >> 6, lane = t & 63;
    const int q = lane >> 4, l15 = lane & 15;
    const int kb = (t >> 4) & 3;              // k-chunk 0..3 (8 k each)
    const int rb = (t & 15) | (w << 4);       // 0..63: A row / B n-pair
    const int k0 = ks * 4096;

    const float* Ag = x + (size_t)(mt * 64 + rb) * XD_ + k0 + kb * 8;
    const float* Bg = Wg1 + (size_t)(k0 + kb * 8) * G1_ + nt * 128 + rb * 2;

    floatx4 acc[4][2];
    #pragma unroll
    for (int i = 0; i < 4; i++)
        #pragma unroll
        for (int j = 0; j < 2; j++) acc[i][j] = (floatx4){0.f, 0.f, 0.f, 0.f};

    for (int kt = 0; kt < 4096; kt += 32) {
        // ---- stage A (64 x 32): this thread: row rb, k = kb*8..+7
        {
            float c[8];
            float4 v0 = *(const float4*)(Ag + kt);
            float4 v1 = *(const float4*)(Ag + kt + 4);
            c[0]=v0.x; c[1]=v0.y; c[2]=v0.z; c[3]=v0.w;
            c[4]=v1.x; c[5]=v1.y; c[6]=v1.z; c[7]=v1.w;
            short8v h, l; split8(c, h, l);
            int idx = (kb * 64 + (rb ^ kb)) * 8;
            *(short8v*)&Ah[idx] = h;
            *(short8v*)&Al[idx] = l;
        }
        // ---- stage B (32 x 128): this thread: cols rb*2, rb*2+1, rows kb*8..+7
        {
            float c0[8], c1[8];
            const float* p = Bg + (size_t)kt * G1_;
            #pragma unroll
            for (int kk = 0; kk < 8; kk++) {
                float2 v = *(const float2*)(p + (size_t)kk * G1_);
                c0[kk] = v.x; c1[kk] = v.y;
            }
            short8v h0, l0, h1, l1;
            split8(c0, h0, l0); split8(c1, h1, l1);
            int n0i = rb * 2;
            int i0 = (kb * 128 + (n0i ^ kb)) * 8;
            int i1 = (kb * 128 + ((n0i + 1) ^ kb)) * 8;
            *(short8v*)&Bh[i0] = h0; *(short8v*)&Bl[i0] = l0;
            *(short8v*)&Bh[i1] = h1; *(short8v*)&Bl[i1] = l1;
        }
        __syncthreads();
        // ---- fragments + MFMA: wave w covers n = w*32..+31, m = 0..63
        short8v af[4], alf[4], bf[2], blf[2];
        #pragma unroll
        for (int i = 0; i < 4; i++) {
            int m = i * 16 + l15;
            int idx = (q * 64 + (m ^ q)) * 8;
            af[i]  = *(const short8v*)&Ah[idx];
            alf[i] = *(const short8v*)&Al[idx];
        }
        #pragma unroll
        for (int j = 0; j < 2; j++) {
            int n = w * 32 + j * 16 + l15;
            int idx = (q * 128 + (n ^ q)) * 8;
            bf[j]  = *(const short8v*)&Bh[idx];
            blf[j] = *(const short8v*)&Bl[idx];
        }
        #pragma unroll
        for (int i = 0; i < 4; i++)
            #pragma unroll
            for (int j = 0; j < 2; j++) {
                acc[i][j] = __builtin_amdgcn_mfma_f32_16x16x32_bf16(af[i],  bf[j],  acc[i][j], 0, 0, 0);
                acc[i][j] = __builtin_amdgcn_mfma_f32_16x16x32_bf16(af[i],  blf[j], acc[i][j], 0, 0, 0);
                acc[i][j] = __builtin_amdgcn_mfma_f32_16x16x32_bf16(alf[i], bf[j],  acc[i][j], 0, 0, 0);
            }
        __syncthreads();
    }
    // epilogue: C layout col=lane&15, row=q*4+reg
    float* P = part + (size_t)ks * (B_ * G1_) + (size_t)(mt * 64) * G1_ + nt * 128;
    #pragma unroll
    for (int i = 0; i < 4; i++)
        #pragma unroll
        for (int j = 0; j < 2; j++) {
            int col = w * 32 + j * 16 + l15;
            #pragma unroll
            for (int r = 0; r < 4; r++) {
                int row = i * 16 + q * 4 + r;
                P[(size_t)row * G1_ + col] = acc[i][j][r];
            }
        }
}

// K1b: reduce 8 split-K partials + bias + elu -> G[512,1024]
__global__ __launch_bounds__(256) void k_red1(const float* __restrict__ part,
                                              const float* __restrict__ bg1,
                                              float* __restrict__ G) {
    int idx = blockIdx.x * 256 + threadIdx.x;  // 524288 total
    const int S = B_ * G1_;
    float s = bg1[idx & (G1_ - 1)];
    #pragma unroll
    for (int k = 0; k < 8; k++) s += part[idx + (size_t)k * S];
    G[idx] = eluf(s);
}

// ---------------------------------------------------------------------------
// K2: h = elu(G[512,1024] @ Wg2[1024,512] + bg2)   fp32 vector, grid (8,8)
// ---------------------------------------------------------------------------
__global__ __launch_bounds__(256) void k_gemm2(const float* __restrict__ G,
                                               const float* __restrict__ Wg2,
                                               const float* __restrict__ bg2,
                                               float* __restrict__ h) {
    __shared__ float As[32][64];
    __shared__ float Bs[32][64];
    const int mt = blockIdx.x, nt = blockIdx.y;
    const int t = threadIdx.x;
    const int trow = t >> 4, tcol = t & 15;
    const int K = G1_, N = PD_;

    float acc[4][4] = {};
    const float* Ag = G + (size_t)(mt * 64) * K;
    const float* Bg = Wg2 + nt * 64;

    for (int kt = 0; kt < K; kt += 32) {
        #pragma unroll
        for (int i = 0; i < 2; i++) {
            int id = i * 256 + t;
            int r = id >> 3;
            int c4 = (id & 7) * 4;
            float4 v = *(const float4*)(Ag + (size_t)r * K + kt + c4);
            As[c4 + 0][r] = v.x; As[c4 + 1][r] = v.y;
            As[c4 + 2][r] = v.z; As[c4 + 3][r] = v.w;
        }
        #pragma unroll
        for (int i = 0; i < 2; i++) {
            int id = i * 256 + t;
            int r = id >> 4;
            int c4 = (id & 15) * 4;
            *(float4*)&Bs[r][c4] = *(const float4*)(Bg + (size_t)(kt + r) * N + c4);
        }
        __syncthreads();
        #pragma unroll
        for (int k = 0; k < 32; k++) {
            float4 av = *(const float4*)&As[k][trow * 4];
            float4 bv = *(const float4*)&Bs[k][tcol * 4];
            float a[4] = {av.x, av.y, av.z, av.w};
            float b[4] = {bv.x, bv.y, bv.z, bv.w};
            #pragma unroll
            for (int i = 0; i < 4; i++)
                #pragma unroll
                for (int j = 0; j < 4; j++)
                    acc[i][j] = fmaf(a[i], b[j], acc[i][j]);
        }
        __syncthreads();
    }
    #pragma unroll
    for (int i = 0; i < 4; i++) {
        int r = mt * 64 + trow * 4 + i;
        int c = nt * 64 + tcol * 4;
        #pragma unroll
        for (int j = 0; j < 4; j++)
            h[(size_t)r * PD_ + c + j] = eluf(acc[i][j] + bg2[c + j]);
    }
}

// ---------------------------------------------------------------------------
// K3: hWh[b,d,h] = sum_p h[b,p] * Wh[d,p,h] — split-bf16 MFMA
// grid (64 d, 8 mt), 256 thr. Tile 64x128, K=512, BK=32.
// ---------------------------------------------------------------------------
__global__ __launch_bounds__(256) void k_hwh_m(const float* __restrict__ h,
                                               const float* __restrict__ Wh,
                                               float* __restrict__ hWh) {
    __shared__ ushort Ah[4 * 64 * 8], Al[4 * 64 * 8];
    __shared__ ushort Bh[4 * 128 * 8], Bl[4 * 128 * 8];
    const int d = blockIdx.x, mt = blockIdx.y;
    const int t = threadIdx.x;
    const int w = t >> 6, lane = t & 63;
    const int q = lane >> 4, l15 = lane & 15;
    const int kb = (t >> 4) & 3;
    const int rb = (t & 15) | (w << 4);

    const float* Ag = h + (size_t)(mt * 64 + rb) * PD_ + kb * 8;
    const float* Bg = Wh + (size_t)d * (PD_ * H_) + (size_t)(kb * 8) * H_ + rb * 2;

    floatx4 acc[4][2];
    #pragma unroll
    for (int i = 0; i < 4; i++)
        #pragma unroll
        for (int j = 0; j < 2; j++) acc[i][j] = (floatx4){0.f, 0.f, 0.f, 0.f};

    for (int kt = 0; kt < PD_; kt += 32) {
        {
            float c[8];
            float4 v0 = *(const float4*)(Ag + kt);
            float4 v1 = *(const float4*)(Ag + kt + 4);
            c[0]=v0.x; c[1]=v0.y; c[2]=v0.z; c[3]=v0.w;
            c[4]=v1.x; c[5]=v1.y; c[6]=v1.z; c[7]=v1.w;
            short8v hh, ll; split8(c, hh, ll);
            int idx = (kb * 64 + (rb ^ kb)) * 8;
            *(short8v*)&Ah[idx] = hh;
            *(short8v*)&Al[idx] = ll;
        }
        {
            float c0[8], c1[8];
            const float* p = Bg + (size_t)kt * H_;
            #pragma unroll
            for (int kk = 0; kk < 8; kk++) {
                float2 v = *(const float2*)(p + (size_t)kk * H_);
                c0[kk] = v.x; c1[kk] = v.y;
            }
            short8v h0, l0, h1, l1;
            split8(c0, h0, l0); split8(c1, h1, l1);
            int n0i = rb * 2;
            int i0 = (kb * 128 + (n0i ^ kb)) * 8;
            int i1 = (kb * 128 + ((n0i + 1) ^ kb)) * 8;
            *(short8v*)&Bh[i0] = h0; *(short8v*)&Bl[i0] = l0;
            *(short8v*)&Bh[i1] = h1; *(short8v*)&Bl[i1] = l1;
        }
        __syncthreads();
        short8v af[4], alf[4], bf[2], blf[2];
        #pragma unroll
        for (int i = 0; i < 4; i++) {
            int m = i * 16 + l15;
            int idx = (q * 64 + (m ^ q)) * 8;
            af[i]  = *(const short8v*)&Ah[idx];
            alf[i] = *(const short8v*)&Al[idx];
        }
        #pragma unroll
        for (int j = 0; j < 2; j++) {
            int n = w * 32 + j * 16 + l15;
            int idx = (q * 128 + (n ^ q)) * 8;
            bf[j]  = *(const short8v*)&Bh[idx];
            blf[j] = *(const short8v*)&Bl[idx];
        }
        #pragma unroll
        for (int i = 0; i < 4; i++)
            #pragma unroll
            for (int j = 0; j < 2; j++) {
                acc[i][j] = __builtin_amdgcn_mfma_f32_16x16x32_bf16(af[i],  bf[j],  acc[i][j], 0, 0, 0);
                acc[i][j] = __builtin_amdgcn_mfma_f32_16x16x32_bf16(af[i],  blf[j], acc[i][j], 0, 0, 0);
                acc[i][j] = __builtin_amdgcn_mfma_f32_16x16x32_bf16(alf[i], bf[j],  acc[i][j], 0, 0, 0);
            }
        __syncthreads();
    }
    // epilogue -> hWh[b][d][hcol]
    #pragma unroll
    for (int i = 0; i < 4; i++)
        #pragma unroll
        for (int j = 0; j < 2; j++) {
            int col = w * 32 + j * 16 + l15;
            #pragma unroll
            for (int r = 0; r < 4; r++) {
                int row = i * 16 + q * 4 + r;
                int b = mt * 64 + row;
                hWh[(size_t)b * (D_ * H_) + d * H_ + col] = acc[i][j][r];
            }
        }
}

// ---------------------------------------------------------------------------
// K4: heads. grid (8 bchunks, 64 d). Two passes (joint, marg). fp32 vector.
// ---------------------------------------------------------------------------
__global__ __launch_bounds__(256) void k_heads(const float* __restrict__ hWh,
                                               const float* __restrict__ z,
                                               const int* __restrict__ perm,
                                               const float* __restrict__ Wz,
                                               const float* __restrict__ b1,
                                               const float* __restrict__ W2,
                                               const float* __restrict__ b2,
                                               const float* __restrict__ W3,
                                               const float* __restrict__ b3,
                                               float* __restrict__ jpart,
                                               float* __restrict__ epart) {
    const int chunk = blockIdx.x;   // 0..7
    const int d = blockIdx.y;       // 0..63
    const int t = threadIdx.x;
    const int b0 = chunk * 64;
    __shared__ float a1T[128][64];  // [h][b]
    __shared__ float Bs[32][128];
    __shared__ float sred[64][16];
    const int trow = t >> 4, tcol = t & 15;
    const float* W2d = W2 + (size_t)d * H_ * H_;
    const float* Wzd = Wz + d * H_;
    const float* b1d = b1 + d * H_;
    const float* b2d = b2 + d * H_;
    const float* W3d = W3 + d * H_;

    float result0 = 0.f, result1 = 0.f;
    for (int pass = 0; pass < 2; pass++) {
        __syncthreads();
        {
            int i = t >> 2;
            int bb = b0 + i;
            int src = (pass == 0) ? bb : perm[bb];
            float zv = z[bb * D_ + d];
            const float* hrow = hWh + (size_t)src * (D_ * H_) + d * H_;
            int h0 = (t & 3) * 32;
            #pragma unroll
            for (int hh = 0; hh < 32; hh += 4) {
                float4 v = *(const float4*)(hrow + h0 + hh);
                float4 w4 = *(const float4*)(Wzd + h0 + hh);
                float4 bb1 = *(const float4*)(b1d + h0 + hh);
                a1T[h0 + hh + 0][i] = eluf(v.x + zv * w4.x + bb1.x);
                a1T[h0 + hh + 1][i] = eluf(v.y + zv * w4.y + bb1.y);
                a1T[h0 + hh + 2][i] = eluf(v.z + zv * w4.z + bb1.z);
                a1T[h0 + hh + 3][i] = eluf(v.w + zv * w4.w + bb1.w);
            }
        }
        __syncthreads();
        float acc[4][8] = {};
        for (int kt = 0; kt < H_; kt += 32) {
            #pragma unroll
            for (int i2 = 0; i2 < 4; i2++) {
                int id = i2 * 256 + t;
                int r = id >> 5;
                int c4 = (id & 31) * 4;
                *(float4*)&Bs[r][c4] = *(const float4*)(W2d + (size_t)(kt + r) * H_ + c4);
            }
            __syncthreads();
            #pragma unroll
            for (int k = 0; k < 32; k++) {
                float4 av = *(const float4*)&a1T[kt + k][trow * 4];
                float4 bv0 = *(const float4*)&Bs[k][tcol * 8];
                float4 bv1 = *(const float4*)&Bs[k][tcol * 8 + 4];
                float a[4] = {av.x, av.y, av.z, av.w};
                float b[8] = {bv0.x, bv0.y, bv0.z, bv0.w, bv1.x, bv1.y, bv1.z, bv1.w};
                #pragma unroll
                for (int i = 0; i < 4; i++)
                    #pragma unroll
                    for (int j = 0; j < 8; j++)
                        acc[i][j] = fmaf(a[i], b[j], acc[i][j]);
            }
            __syncthreads();
        }
        #pragma unroll
        for (int i = 0; i < 4; i++) {
            float s = 0.f;
            #pragma unroll
            for (int j = 0; j < 8; j++) {
                int c = tcol * 8 + j;
                float a2v = eluf(acc[i][j] + b2d[c]);
                s = fmaf(a2v, W3d[c], s);
            }
            sred[trow * 4 + i][tcol] = s;
        }
        __syncthreads();
        float val = 0.f;
        if (t < 64) {
            float s = b3[d];
            #pragma unroll
            for (int c = 0; c < 16; c++) s += sred[t][c];
            val = (pass == 0) ? s : expf(s);
            #pragma unroll
            for (int off = 32; off > 0; off >>= 1)
                val += __shfl_down(val, off, 64);
        }
        if (t == 0) { if (pass == 0) result0 = val; else result1 = val; }
    }
    if (t == 0) {
        jpart[d * 8 + chunk] = result0;
        epart[d * 8 + chunk] = result1;
    }
}

// K5: final scalar. 1 block, 64 threads (one per d).
__global__ void k_final(const float* __restrict__ jpart,
                        const float* __restrict__ epart,
                        float* __restrict__ out) {
    int t = threadIdx.x;
    float mj = 0.f, me = 0.f;
    #pragma unroll
    for (int c = 0; c < 8; c++) { mj += jpart[t * 8 + c]; me += epart[t * 8 + c]; }
    mj *= (1.f / 512.f);
    me *= (1.f / 512.f);
    float mi = mj - logf(me);
    #pragma unroll
    for (int off = 32; off > 0; off >>= 1) mi += __shfl_down(mi, off, 64);
    if (t == 0) out[0] = -mi * (1.f / 64.f);
}

extern "C" void kernel_launch(void* const* d_in, const int* in_sizes, int n_in,
                              void* d_out, int out_size, void* d_ws, size_t ws_size,
                              hipStream_t stream) {
    const float* x   = (const float*)d_in[0];
    const float* z   = (const float*)d_in[1];
    const int*  perm = (const int*)d_in[2];
    const float* Wg1 = (const float*)d_in[3];
    const float* bg1 = (const float*)d_in[4];
    const float* Wg2 = (const float*)d_in[5];
    const float* bg2 = (const float*)d_in[6];
    const float* Wh  = (const float*)d_in[7];
    const float* Wz  = (const float*)d_in[8];
    const float* b1  = (const float*)d_in[9];
    const float* W2  = (const float*)d_in[10];
    const float* b2  = (const float*)d_in[11];
    const float* W3  = (const float*)d_in[12];
    const float* b3  = (const float*)d_in[13];
    float* out = (float*)d_out;

    float* ws = (float*)d_ws;
    float* G     = ws;                        // 524288 floats
    float* h     = ws + 524288;               // 262144
    float* hWh   = ws + 786432;               // 4194304
    float* part  = ws + 786432;               // 8 x 524288 = 4194304 (overlaps hWh; dead before K3)
    float* jpart = ws + 786432 + 4194304;     // 512
    float* epart = jpart + 512;               // 512

    k_gemm1m<<<dim3(8, 8, 8), 256, 0, stream>>>(x, Wg1, part);
    k_red1<<<2048, 256, 0, stream>>>(part, bg1, G);
    k_gemm2<<<dim3(8, 8), 256, 0, stream>>>(G, Wg2, bg2, h);
    k_hwh_m<<<dim3(64, 8), 256, 0, stream>>>(h, Wh, hWh);
    k_heads<<<dim3(8, 64), 256, 0, stream>>>(hWh, z, perm, Wz, b1, W2, b2, W3, b3,
                                             jpart, epart);
    k_final<<<1, 64, 0, stream>>>(jpart, epart, out);
}

// Round 3
// 428.489 us; speedup vs baseline: 2.2090x; 1.3166x over previous
//
#include <hip/hip_runtime.h>
#include <hip/hip_bf16.h>
#include <math.h>

// Problem constants
#define B_  512
#define XD_ 32768
#define PD_ 512
#define D_  64
#define H_  128
#define G1_ 1024

typedef __attribute__((ext_vector_type(8))) short short8v;
typedef __attribute__((ext_vector_type(4))) float floatx4;

__device__ __forceinline__ float eluf(float v) { return v > 0.f ? v : expm1f(v); }

// Truncation split: hi = c with low 16 mantissa bits zeroed (exact residual),
// lo = bf16-trunc of residual. Packed pairwise with v_perm_b32 (~3 ops/value).
__device__ __forceinline__ void split8t(const float* c, short8v& h, short8v& l) {
    unsigned hu[8], lu[8];
    #pragma unroll
    for (int j = 0; j < 8; j++) {
        unsigned u = __float_as_uint(c[j]);
        hu[j] = u & 0xFFFF0000u;
        float res = c[j] - __uint_as_float(hu[j]);
        lu[j] = __float_as_uint(res);
    }
    uint4 hp, lp;
    hp.x = __builtin_amdgcn_perm(hu[1], hu[0], 0x07060302u);
    hp.y = __builtin_amdgcn_perm(hu[3], hu[2], 0x07060302u);
    hp.z = __builtin_amdgcn_perm(hu[5], hu[4], 0x07060302u);
    hp.w = __builtin_amdgcn_perm(hu[7], hu[6], 0x07060302u);
    lp.x = __builtin_amdgcn_perm(lu[1], lu[0], 0x07060302u);
    lp.y = __builtin_amdgcn_perm(lu[3], lu[2], 0x07060302u);
    lp.z = __builtin_amdgcn_perm(lu[5], lu[4], 0x07060302u);
    lp.w = __builtin_amdgcn_perm(lu[7], lu[6], 0x07060302u);
    h = __builtin_bit_cast(short8v, hp);
    l = __builtin_bit_cast(short8v, lp);
}

// ---------------------------------------------------------------------------
// K1: split-bf16 MFMA GEMM  part[ks] = x[512,32768] @ Wg1[32768,1024] slice
// grid (8 nt, 8 mt, 16 ks), 256 thr. Tile 64x128, BK=32, K-slice 2048.
// Register prefetch of next tile; truncation split; 3-term MFMA.
// ---------------------------------------------------------------------------
__global__ __launch_bounds__(256, 3) void k_gemm1m(const float* __restrict__ x,
                                                   const float* __restrict__ Wg1,
                                                   float* __restrict__ part) {
    __shared__ ushort Ah[4 * 64 * 8], Al[4 * 64 * 8];     // 4 KB each
    __shared__ ushort Bh[4 * 128 * 8], Bl[4 * 128 * 8];   // 8 KB each
    const int nt = blockIdx.x, mt = blockIdx.y, ks = blockIdx.z;
    const int t = threadIdx.x;
    const int w = t >> 6, lane = t & 63;
    const int q = lane >> 4, l15 = lane & 15;
    const int kb = (t >> 4) & 3;
    const int rb = (t & 15) | (w << 4);
    const int KS = 2048;
    const int k0 = ks * KS;

    const float* Ag = x + (size_t)(mt * 64 + rb) * XD_ + k0 + kb * 8;
    const float* Bg = Wg1 + (size_t)(k0 + kb * 8) * G1_ + nt * 128 + rb * 2;

    floatx4 acc[4][2];
    #pragma unroll
    for (int i = 0; i < 4; i++)
        #pragma unroll
        for (int j = 0; j < 2; j++) acc[i][j] = (floatx4){0.f, 0.f, 0.f, 0.f};

    // preload kt=0
    float4 pa0 = *(const float4*)(Ag);
    float4 pa1 = *(const float4*)(Ag + 4);
    float2 pb[8];
    #pragma unroll
    for (int kk = 0; kk < 8; kk++) pb[kk] = *(const float2*)(Bg + (size_t)kk * G1_);

    for (int kt = 0; kt < KS; kt += 32) {
        // ---- convert current registers
        float ca[8] = {pa0.x, pa0.y, pa0.z, pa0.w, pa1.x, pa1.y, pa1.z, pa1.w};
        float c0[8], c1[8];
        #pragma unroll
        for (int kk = 0; kk < 8; kk++) { c0[kk] = pb[kk].x; c1[kk] = pb[kk].y; }
        short8v ah, al, bh0, bl0, bh1, bl1;
        split8t(ca, ah, al);
        split8t(c0, bh0, bl0);
        split8t(c1, bh1, bl1);
        // ---- prefetch next tile (in flight across MFMA block)
        if (kt + 32 < KS) {
            pa0 = *(const float4*)(Ag + kt + 32);
            pa1 = *(const float4*)(Ag + kt + 36);
            const float* p = Bg + (size_t)(kt + 32) * G1_;
            #pragma unroll
            for (int kk = 0; kk < 8; kk++) pb[kk] = *(const float2*)(p + (size_t)kk * G1_);
        }
        // ---- stash converted tile in LDS (fragment layout, swizzled)
        {
            int idx = (kb * 64 + (rb ^ kb)) * 8;
            *(short8v*)&Ah[idx] = ah;
            *(short8v*)&Al[idx] = al;
            int n0i = rb * 2;
            int i0 = (kb * 128 + (n0i ^ kb)) * 8;
            int i1 = (kb * 128 + ((n0i + 1) ^ kb)) * 8;
            *(short8v*)&Bh[i0] = bh0; *(short8v*)&Bl[i0] = bl0;
            *(short8v*)&Bh[i1] = bh1; *(short8v*)&Bl[i1] = bl1;
        }
        __syncthreads();
        // ---- fragments + MFMA: wave w covers n = w*32..+31, m = 0..63
        short8v af[4], alf[4], bf[2], blf[2];
        #pragma unroll
        for (int i = 0; i < 4; i++) {
            int m = i * 16 + l15;
            int idx = (q * 64 + (m ^ q)) * 8;
            af[i]  = *(const short8v*)&Ah[idx];
            alf[i] = *(const short8v*)&Al[idx];
        }
        #pragma unroll
        for (int j = 0; j < 2; j++) {
            int n = w * 32 + j * 16 + l15;
            int idx = (q * 128 + (n ^ q)) * 8;
            bf[j]  = *(const short8v*)&Bh[idx];
            blf[j] = *(const short8v*)&Bl[idx];
        }
        #pragma unroll
        for (int i = 0; i < 4; i++)
            #pragma unroll
            for (int j = 0; j < 2; j++) {
                acc[i][j] = __builtin_amdgcn_mfma_f32_16x16x32_bf16(af[i],  bf[j],  acc[i][j], 0, 0, 0);
                acc[i][j] = __builtin_amdgcn_mfma_f32_16x16x32_bf16(af[i],  blf[j], acc[i][j], 0, 0, 0);
                acc[i][j] = __builtin_amdgcn_mfma_f32_16x16x32_bf16(alf[i], bf[j],  acc[i][j], 0, 0, 0);
            }
        __syncthreads();
    }
    // epilogue: C layout col=lane&15, row=q*4+reg
    float* P = part + (size_t)ks * (B_ * G1_) + (size_t)(mt * 64) * G1_ + nt * 128;
    #pragma unroll
    for (int i = 0; i < 4; i++)
        #pragma unroll
        for (int j = 0; j < 2; j++) {
            int col = w * 32 + j * 16 + l15;
            #pragma unroll
            for (int r = 0; r < 4; r++) {
                int row = i * 16 + q * 4 + r;
                P[(size_t)row * G1_ + col] = acc[i][j][r];
            }
        }
}

// K1b: reduce 16 split-K partials + bias + elu -> G as bf16 hi/lo planes
__global__ __launch_bounds__(256) void k_red1(const float* __restrict__ part,
                                              const float* __restrict__ bg1,
                                              ushort* __restrict__ Gh,
                                              ushort* __restrict__ Gl) {
    int idx = (blockIdx.x * 256 + threadIdx.x) * 8;  // 524288 total / 8
    const int S = B_ * G1_;
    float c[8] = {};
    #pragma unroll
    for (int k = 0; k < 16; k++) {
        const float* p = part + (size_t)k * S + idx;
        float4 v0 = *(const float4*)p, v1 = *(const float4*)(p + 4);
        c[0] += v0.x; c[1] += v0.y; c[2] += v0.z; c[3] += v0.w;
        c[4] += v1.x; c[5] += v1.y; c[6] += v1.z; c[7] += v1.w;
    }
    int cb = idx & (G1_ - 1);
    float4 b0 = *(const float4*)(bg1 + cb), b1v = *(const float4*)(bg1 + cb + 4);
    c[0] = eluf(c[0] + b0.x); c[1] = eluf(c[1] + b0.y);
    c[2] = eluf(c[2] + b0.z); c[3] = eluf(c[3] + b0.w);
    c[4] = eluf(c[4] + b1v.x); c[5] = eluf(c[5] + b1v.y);
    c[6] = eluf(c[6] + b1v.z); c[7] = eluf(c[7] + b1v.w);
    short8v h, l; split8t(c, h, l);
    *(short8v*)(Gh + idx) = h;
    *(short8v*)(Gl + idx) = l;
}

// ---------------------------------------------------------------------------
// K2: part2[ks] = G[512,1024] @ Wg2[1024,512] slice — split-bf16 MFMA
// grid (8 nt, 8 mt, 8 ks), tile 64x64, K-slice 128 (4 iters).
// A from pre-split Gh/Gl planes (pure copy staging); B fused split.
// ---------------------------------------------------------------------------
__global__ __launch_bounds__(256, 2) void k_gemm2m(const ushort* __restrict__ Gh,
                                                   const ushort* __restrict__ Gl,
                                                   const float* __restrict__ Wg2,
                                                   float* __restrict__ part2) {
    __shared__ ushort Ah[4 * 64 * 8], Al[4 * 64 * 8];   // 4 KB each
    __shared__ ushort Bh[4 * 64 * 8], Bl[4 * 64 * 8];   // 4 KB each
    const int nt = blockIdx.x, mt = blockIdx.y, ks = blockIdx.z;
    const int t = threadIdx.x;
    const int w = t >> 6, lane = t & 63;
    const int q = lane >> 4, l15 = lane & 15;
    const int kb = (t >> 4) & 3;
    const int rb = (t & 15) | (w << 4);
    const int k0 = ks * 128;

    // B staging map: col c = t&63, k-row group g = t>>6 (rows g*8..+7)
    const int cB = t & 63, g = t >> 6;

    floatx4 acc[4];
    #pragma unroll
    for (int i = 0; i < 4; i++) acc[i] = (floatx4){0.f, 0.f, 0.f, 0.f};

    for (int kt = 0; kt < 128; kt += 32) {
        // A: copy pre-split planes
        {
            const ushort* pH = Gh + (size_t)(mt * 64 + rb) * G1_ + k0 + kt + kb * 8;
            const ushort* pL = Gl + (size_t)(mt * 64 + rb) * G1_ + k0 + kt + kb * 8;
            uint4 vh = *(const uint4*)pH;
            uint4 vl = *(const uint4*)pL;
            int idx = (kb * 64 + (rb ^ kb)) * 8;
            *(uint4*)&Ah[idx] = vh;
            *(uint4*)&Al[idx] = vl;
        }
        // B: fused split of Wg2 rows k0+kt+g*8..+7, col nt*64+cB
        {
            float c[8];
            const float* p = Wg2 + (size_t)(k0 + kt + g * 8) * PD_ + nt * 64 + cB;
            #pragma unroll
            for (int kk = 0; kk < 8; kk++) c[kk] = p[(size_t)kk * PD_];
            short8v h, l; split8t(c, h, l);
            int idx = (g * 64 + (cB ^ g)) * 8;
            *(short8v*)&Bh[idx] = h;
            *(short8v*)&Bl[idx] = l;
        }
        __syncthreads();
        short8v af[4], alf[4], bf, blf;
        #pragma unroll
        for (int i = 0; i < 4; i++) {
            int m = i * 16 + l15;
            int idx = (q * 64 + (m ^ q)) * 8;
            af[i]  = *(const short8v*)&Ah[idx];
            alf[i] = *(const short8v*)&Al[idx];
        }
        {
            int n = w * 16 + l15;
            int idx = (q * 64 + (n ^ q)) * 8;
            bf  = *(const short8v*)&Bh[idx];
            blf = *(const short8v*)&Bl[idx];
        }
        #pragma unroll
        for (int i = 0; i < 4; i++) {
            acc[i] = __builtin_amdgcn_mfma_f32_16x16x32_bf16(af[i],  bf,  acc[i], 0, 0, 0);
            acc[i] = __builtin_amdgcn_mfma_f32_16x16x32_bf16(af[i],  blf, acc[i], 0, 0, 0);
            acc[i] = __builtin_amdgcn_mfma_f32_16x16x32_bf16(alf[i], bf,  acc[i], 0, 0, 0);
        }
        __syncthreads();
    }
    float* P = part2 + (size_t)ks * (B_ * PD_) + (size_t)(mt * 64) * PD_ + nt * 64;
    #pragma unroll
    for (int i = 0; i < 4; i++) {
        int col = w * 16 + l15;
        #pragma unroll
        for (int r = 0; r < 4; r++) {
            int row = i * 16 + q * 4 + r;
            P[(size_t)row * PD_ + col] = acc[i][r];
        }
    }
}

// K2b: reduce 8 partials + bias + elu -> h as bf16 hi/lo planes
__global__ __launch_bounds__(256) void k_red2(const float* __restrict__ part2,
                                              const float* __restrict__ bg2,
                                              ushort* __restrict__ hh,
                                              ushort* __restrict__ hl) {
    int idx = (blockIdx.x * 256 + threadIdx.x) * 8;  // 262144 total / 8
    const int S = B_ * PD_;
    float c[8] = {};
    #pragma unroll
    for (int k = 0; k < 8; k++) {
        const float* p = part2 + (size_t)k * S + idx;
        float4 v0 = *(const float4*)p, v1 = *(const float4*)(p + 4);
        c[0] += v0.x; c[1] += v0.y; c[2] += v0.z; c[3] += v0.w;
        c[4] += v1.x; c[5] += v1.y; c[6] += v1.z; c[7] += v1.w;
    }
    int cb = idx & (PD_ - 1);
    float4 b0 = *(const float4*)(bg2 + cb), b1v = *(const float4*)(bg2 + cb + 4);
    c[0] = eluf(c[0] + b0.x); c[1] = eluf(c[1] + b0.y);
    c[2] = eluf(c[2] + b0.z); c[3] = eluf(c[3] + b0.w);
    c[4] = eluf(c[4] + b1v.x); c[5] = eluf(c[5] + b1v.y);
    c[6] = eluf(c[6] + b1v.z); c[7] = eluf(c[7] + b1v.w);
    short8v h, l; split8t(c, h, l);
    *(short8v*)(hh + idx) = h;
    *(short8v*)(hl + idx) = l;
}

// ---------------------------------------------------------------------------
// K3: hWh[b,d,h] = sum_p h[b,p] * Wh[d,p,h] — split-bf16 MFMA + prefetch
// grid (64 d, 8 mt), tile 64x128, K=512 (16 iters). A pre-split; B fused.
// ---------------------------------------------------------------------------
__global__ __launch_bounds__(256, 2) void k_hwh_m(const ushort* __restrict__ hh,
                                                  const ushort* __restrict__ hl,
                                                  const float* __restrict__ Wh,
                                                  float* __restrict__ hWh) {
    __shared__ ushort Ah[4 * 64 * 8], Al[4 * 64 * 8];
    __shared__ ushort Bh[4 * 128 * 8], Bl[4 * 128 * 8];
    const int d = blockIdx.x, mt = blockIdx.y;
    const int t = threadIdx.x;
    const int w = t >> 6, lane = t & 63;
    const int q = lane >> 4, l15 = lane & 15;
    const int kb = (t >> 4) & 3;
    const int rb = (t & 15) | (w << 4);

    const ushort* AgH = hh + (size_t)(mt * 64 + rb) * PD_ + kb * 8;
    const ushort* AgL = hl + (size_t)(mt * 64 + rb) * PD_ + kb * 8;
    const float* Bg = Wh + (size_t)d * (PD_ * H_) + (size_t)(kb * 8) * H_ + rb * 2;

    floatx4 acc[4][2];
    #pragma unroll
    for (int i = 0; i < 4; i++)
        #pragma unroll
        for (int j = 0; j < 2; j++) acc[i][j] = (floatx4){0.f, 0.f, 0.f, 0.f};

    uint4 pah = *(const uint4*)(AgH);
    uint4 pal = *(const uint4*)(AgL);
    float2 pb[8];
    #pragma unroll
    for (int kk = 0; kk < 8; kk++) pb[kk] = *(const float2*)(Bg + (size_t)kk * H_);

    for (int kt = 0; kt < PD_; kt += 32) {
        float c0[8], c1[8];
        #pragma unroll
        for (int kk = 0; kk < 8; kk++) { c0[kk] = pb[kk].x; c1[kk] = pb[kk].y; }
        short8v bh0, bl0, bh1, bl1;
        split8t(c0, bh0, bl0);
        split8t(c1, bh1, bl1);
        uint4 ah = pah, al = pal;
        // prefetch next
        if (kt + 32 < PD_) {
            pah = *(const uint4*)(AgH + kt + 32);
            pal = *(const uint4*)(AgL + kt + 32);
            const float* p = Bg + (size_t)(kt + 32) * H_;
            #pragma unroll
            for (int kk = 0; kk < 8; kk++) pb[kk] = *(const float2*)(p + (size_t)kk * H_);
        }
        {
            int idx = (kb * 64 + (rb ^ kb)) * 8;
            *(uint4*)&Ah[idx] = ah;
            *(uint4*)&Al[idx] = al;
            int n0i = rb * 2;
            int i0 = (kb * 128 + (n0i ^ kb)) * 8;
            int i1 = (kb * 128 + ((n0i + 1) ^ kb)) * 8;
            *(short8v*)&Bh[i0] = bh0; *(short8v*)&Bl[i0] = bl0;
            *(short8v*)&Bh[i1] = bh1; *(short8v*)&Bl[i1] = bl1;
        }
        __syncthreads();
        short8v af[4], alf[4], bf[2], blf[2];
        #pragma unroll
        for (int i = 0; i < 4; i++) {
            int m = i * 16 + l15;
            int idx = (q * 64 + (m ^ q)) * 8;
            af[i]  = *(const short8v*)&Ah[idx];
            alf[i] = *(const short8v*)&Al[idx];
        }
        #pragma unroll
        for (int j = 0; j < 2; j++) {
            int n = w * 32 + j * 16 + l15;
            int idx = (q * 128 + (n ^ q)) * 8;
            bf[j]  = *(const short8v*)&Bh[idx];
            blf[j] = *(const short8v*)&Bl[idx];
        }
        #pragma unroll
        for (int i = 0; i < 4; i++)
            #pragma unroll
            for (int j = 0; j < 2; j++) {
                acc[i][j] = __builtin_amdgcn_mfma_f32_16x16x32_bf16(af[i],  bf[j],  acc[i][j], 0, 0, 0);
                acc[i][j] = __builtin_amdgcn_mfma_f32_16x16x32_bf16(af[i],  blf[j], acc[i][j], 0, 0, 0);
                acc[i][j] = __builtin_amdgcn_mfma_f32_16x16x32_bf16(alf[i], bf[j],  acc[i][j], 0, 0, 0);
            }
        __syncthreads();
    }
    #pragma unroll
    for (int i = 0; i < 4; i++)
        #pragma unroll
        for (int j = 0; j < 2; j++) {
            int col = w * 32 + j * 16 + l15;
            #pragma unroll
            for (int r = 0; r < 4; r++) {
                int row = i * 16 + q * 4 + r;
                int b = mt * 64 + row;
                hWh[(size_t)b * (D_ * H_) + d * H_ + col] = acc[i][j][r];
            }
        }
}

// ---------------------------------------------------------------------------
// K4: heads — split-bf16 MFMA. grid (8 bchunks, 64 d), 2 passes.
// a1 built split directly into LDS A-fragment layout; W2 staged split per-kt.
// ---------------------------------------------------------------------------
__global__ __launch_bounds__(256, 2) void k_heads(const float* __restrict__ hWh,
                                                  const float* __restrict__ z,
                                                  const int* __restrict__ perm,
                                                  const float* __restrict__ Wz,
                                                  const float* __restrict__ b1,
                                                  const float* __restrict__ W2,
                                                  const float* __restrict__ b2,
                                                  const float* __restrict__ W3,
                                                  const float* __restrict__ b3,
                                                  float* __restrict__ jpart,
                                                  float* __restrict__ epart) {
    const int chunk = blockIdx.x;   // 0..7
    const int d = blockIdx.y;       // 0..63
    const int t = threadIdx.x;
    const int b0 = chunk * 64;
    __shared__ ushort A1h[16 * 64 * 8];   // 16 KB  [ (kt*4+kq) ][ m ][ 8k ]
    __shared__ ushort A1l[16 * 64 * 8];   // 16 KB
    __shared__ float  BS[4096];           // 16 KB: Bh/Bl staging, aliased as sred
    ushort* Bh = (ushort*)BS;             // 4*128*8 ushort = 8 KB
    ushort* Bl = Bh + 4096;               // 8 KB
    float*  sred = BS;                    // [64][64]

    const int w = t >> 6, lane = t & 63;
    const int q = lane >> 4, l15 = lane & 15;
    const int kb = (t >> 4) & 3;
    const int rb = (t & 15) | (w << 4);

    const float* W2d = W2 + (size_t)d * H_ * H_;
    const float* Wzd = Wz + d * H_;
    const float* b1d = b1 + d * H_;
    const float* b2d = b2 + d * H_;
    const float* W3d = W3 + d * H_;

    float result0 = 0.f, result1 = 0.f;
    for (int pass = 0; pass < 2; pass++) {
        // ---- build a1 (split) into A-fragment LDS layout
        {
            int i = t >> 2;            // b-row 0..63
            int kt = t & 3;            // which 32-k block
            int h0 = kt * 32;
            int bb = b0 + i;
            int src = (pass == 0) ? bb : perm[bb];
            float zv = z[bb * D_ + d];
            const float* hrow = hWh + (size_t)src * (D_ * H_) + d * H_;
            #pragma unroll
            for (int kq = 0; kq < 4; kq++) {
                float c[8];
                int kbase = h0 + kq * 8;
                float4 v0 = *(const float4*)(hrow + kbase);
                float4 v1 = *(const float4*)(hrow + kbase + 4);
                float4 w0 = *(const float4*)(Wzd + kbase);
                float4 w1 = *(const float4*)(Wzd + kbase + 4);
                float4 x0 = *(const float4*)(b1d + kbase);
                float4 x1 = *(const float4*)(b1d + kbase + 4);
                c[0] = eluf(v0.x + zv * w0.x + x0.x);
                c[1] = eluf(v0.y + zv * w0.y + x0.y);
                c[2] = eluf(v0.z + zv * w0.z + x0.z);
                c[3] = eluf(v0.w + zv * w0.w + x0.w);
                c[4] = eluf(v1.x + zv * w1.x + x1.x);
                c[5] = eluf(v1.y + zv * w1.y + x1.y);
                c[6] = eluf(v1.z + zv * w1.z + x1.z);
                c[7] = eluf(v1.w + zv * w1.w + x1.w);
                short8v hv, lv; split8t(c, hv, lv);
                int idx = ((kt * 4 + kq) * 64 + (i ^ kq)) * 8;
                *(short8v*)&A1h[idx] = hv;
                *(short8v*)&A1l[idx] = lv;
            }
        }
        __syncthreads();
        // ---- K loop over 4 x 32 with W2 staging
        floatx4 acc[4][2];
        #pragma unroll
        for (int i = 0; i < 4; i++)
            #pragma unroll
            for (int j = 0; j < 2; j++) acc[i][j] = (floatx4){0.f, 0.f, 0.f, 0.f};
        for (int kt2 = 0; kt2 < 4; kt2++) {
            {
                float c0[8], c1[8];
                const float* p = W2d + (size_t)(kt2 * 32 + kb * 8) * H_ + rb * 2;
                #pragma unroll
                for (int kk = 0; kk < 8; kk++) {
                    float2 v = *(const float2*)(p + (size_t)kk * H_);
                    c0[kk] = v.x; c1[kk] = v.y;
                }
                short8v h0v, l0v, h1v, l1v;
                split8t(c0, h0v, l0v);
                split8t(c1, h1v, l1v);
                int n0i = rb * 2;
                int i0 = (kb * 128 + (n0i ^ kb)) * 8;
                int i1 = (kb * 128 + ((n0i + 1) ^ kb)) * 8;
                *(short8v*)&Bh[i0] = h0v; *(short8v*)&Bl[i0] = l0v;
                *(short8v*)&Bh[i1] = h1v; *(short8v*)&Bl[i1] = l1v;
            }
            __syncthreads();
            short8v af[4], alf[4], bf[2], blf[2];
            #pragma unroll
            for (int i = 0; i < 4; i++) {
                int m = i * 16 + l15;
                int idx = ((kt2 * 4 + q) * 64 + (m ^ q)) * 8;
                af[i]  = *(const short8v*)&A1h[idx];
                alf[i] = *(const short8v*)&A1l[idx];
            }
            #pragma unroll
            for (int j = 0; j < 2; j++) {
                int n = w * 32 + j * 16 + l15;
                int idx = (q * 128 + (n ^ q)) * 8;
                bf[j]  = *(const short8v*)&Bh[idx];
                blf[j] = *(const short8v*)&Bl[idx];
            }
            #pragma unroll
            for (int i = 0; i < 4; i++)
                #pragma unroll
                for (int j = 0; j < 2; j++) {
                    acc[i][j] = __builtin_amdgcn_mfma_f32_16x16x32_bf16(af[i],  bf[j],  acc[i][j], 0, 0, 0);
                    acc[i][j] = __builtin_amdgcn_mfma_f32_16x16x32_bf16(af[i],  blf[j], acc[i][j], 0, 0, 0);
                    acc[i][j] = __builtin_amdgcn_mfma_f32_16x16x32_bf16(alf[i], bf[j],  acc[i][j], 0, 0, 0);
                }
            __syncthreads();
        }
        // ---- epilogue: a2 = elu(acc + b2), partial score = sum a2*W3
        // sred aliases the (now dead) B staging buffer; last loop iter ended
        // with a barrier so all frag reads are done.
        #pragma unroll
        for (int i = 0; i < 4; i++) {
            #pragma unroll
            for (int r = 0; r < 4; r++) {
                int b = i * 16 + q * 4 + r;
                float s = 0.f;
                #pragma unroll
                for (int j = 0; j < 2; j++) {
                    int col = w * 32 + j * 16 + l15;
                    float a2v = eluf(acc[i][j][r] + b2d[col]);
                    s = fmaf(a2v, W3d[col], s);
                }
                sred[b * 64 + w * 16 + l15] = s;
            }
        }
        __syncthreads();
        float val = 0.f;
        if (t < 64) {
            float s = b3[d];
            const float4* row = (const float4*)&sred[t * 64];
            #pragma unroll
            for (int c = 0; c < 16; c++) {
                float4 v = row[c];
                s += v.x + v.y + v.z + v.w;
            }
            val = (pass == 0) ? s : expf(s);
            #pragma unroll
            for (int off = 32; off > 0; off >>= 1)
                val += __shfl_down(val, off, 64);
        }
        if (t == 0) { if (pass == 0) result0 = val; else result1 = val; }
        __syncthreads();   // protect sred / A1 before next pass rebuilds
    }
    if (t == 0) {
        jpart[d * 8 + chunk] = result0;
        epart[d * 8 + chunk] = result1;
    }
}

// K5: final scalar. 1 block, 64 threads (one per d).
__global__ void k_final(const float* __restrict__ jpart,
                        const float* __restrict__ epart,
                        float* __restrict__ out) {
    int t = threadIdx.x;
    float mj = 0.f, me = 0.f;
    #pragma unroll
    for (int c = 0; c < 8; c++) { mj += jpart[t * 8 + c]; me += epart[t * 8 + c]; }
    mj *= (1.f / 512.f);
    me *= (1.f / 512.f);
    float mi = mj - logf(me);
    #pragma unroll
    for (int off = 32; off > 0; off >>= 1) mi += __shfl_down(mi, off, 64);
    if (t == 0) out[0] = -mi * (1.f / 64.f);
}

extern "C" void kernel_launch(void* const* d_in, const int* in_sizes, int n_in,
                              void* d_out, int out_size, void* d_ws, size_t ws_size,
                              hipStream_t stream) {
    const float* x   = (const float*)d_in[0];
    const float* z   = (const float*)d_in[1];
    const int*  perm = (const int*)d_in[2];
    const float* Wg1 = (const float*)d_in[3];
    const float* bg1 = (const float*)d_in[4];
    const float* Wg2 = (const float*)d_in[5];
    const float* bg2 = (const float*)d_in[6];
    const float* Wh  = (const float*)d_in[7];
    const float* Wz  = (const float*)d_in[8];
    const float* b1  = (const float*)d_in[9];
    const float* W2  = (const float*)d_in[10];
    const float* b2  = (const float*)d_in[11];
    const float* W3  = (const float*)d_in[12];
    const float* b3  = (const float*)d_in[13];
    float* out = (float*)d_out;

    char* base = (char*)d_ws;
    // part: 16 x 2 MB = 33,554,432 B. hWh (16.8 MB) and part2 (8.4 MB)
    // overlap it (part is dead after k_red1; hWh/part2 regions disjoint).
    float* part  = (float*)base;
    float* hWh   = (float*)base;                       // 4,194,304 floats
    float* part2 = (float*)(base + 16777216);          // 2,097,152 floats
    ushort* Gh   = (ushort*)(base + 33554432);         // 524288 ushort
    ushort* Gl   = Gh + 524288;
    ushort* hh   = (ushort*)(base + 35651584);         // 262144 ushort
    ushort* hl   = hh + 262144;
    float* jpart = (float*)(base + 36700160);
    float* epart = jpart + 512;

    k_gemm1m<<<dim3(8, 8, 16), 256, 0, stream>>>(x, Wg1, part);
    k_red1<<<256, 256, 0, stream>>>(part, bg1, Gh, Gl);
    k_gemm2m<<<dim3(8, 8, 8), 256, 0, stream>>>(Gh, Gl, Wg2, part2);
    k_red2<<<128, 256, 0, stream>>>(part2, bg2, hh, hl);
    k_hwh_m<<<dim3(64, 8), 256, 0, stream>>>(hh, hl, Wh, hWh);
    k_heads<<<dim3(8, 64), 256, 0, stream>>>(hWh, z, perm, Wz, b1, W2, b2, W3, b3,
                                             jpart, epart);
    k_final<<<1, 64, 0, stream>>>(jpart, epart, out);
}